// Round 1
// baseline (473.219 us; speedup 1.0000x reference)
//
#include <hip/hip_runtime.h>

// FlowNet correlation: out[b,(dy)*9+dx, y, x] = (1/C) sum_c x1[b,c,y,x]*x2[b,c,y+dy-4,x+dx-4]
// B=4 C=256 H=128 W=128, 81 displacements (9x9, radius 4), zero padding.

#define MD 4
constexpr int Bc = 4, Cc = 256, Hc = 128, Wc = 128;
constexpr int TH = 16, TW = 16;          // pixel tile per block
constexpr int NDY = 3;                   // dy values per d-group (3 grid passes)
constexpr int CC = 8;                    // channels staged per chunk (2 per subset)
constexpr int SROWS = TH + NDY - 1;      // 18 x2 rows needed per d-group
constexpr int SCOLS = TW + 2 * MD;       // 24 x2 cols needed
constexpr int SG = 17;                   // acc stride for gy (16+1 pad -> ~2-way banks)
constexpr int STG_SZ = CC * SCOLS * SROWS;   // 3456 floats (13.8 KB)
constexpr int ACC_SZ = NDY * 9 * TW * SG;    // 27*16*17 = 7344 floats (29.4 KB)

__global__ __launch_bounds__(256, 3)
void corr_kernel(const float* __restrict__ x1, const float* __restrict__ x2,
                 float* __restrict__ out)
{
    // stg is column-major per channel: stg[cl][col][row]
    __shared__ float stg[STG_SZ];
    __shared__ float accs[ACC_SZ];

    const int tid  = threadIdx.x;
    const int sub  = tid >> 6;       // channel subset 0..3
    const int lane = tid & 63;
    const int gy   = lane >> 2;      // 0..15  (tile row)
    const int gx   = lane & 3;       // 0..3   (x-group of 4 pixels)

    int bid = blockIdx.x;
    const int g  = bid % 3;  bid /= 3;      // d-group: dy in [3g, 3g+3)
    const int tx = bid & 7;                 // W/TW = 8
    const int ty = (bid >> 3) & 7;          // H/TH = 8
    const int bb = bid >> 6;                // batch
    const int x0 = tx * TW, y0 = ty * TH;

    // zero the LDS accumulator region
    for (int i = tid; i < ACC_SZ; i += 256) accs[i] = 0.f;

    float acc[NDY][9][4];
    #pragma unroll
    for (int j = 0; j < NDY; ++j)
        #pragma unroll
        for (int d = 0; d < 9; ++d)
            #pragma unroll
            for (int p = 0; p < 4; ++p) acc[j][d][p] = 0.f;

    const int rowbase = y0 + 3 * g - 4;   // global y of stg row 0
    const int colbase = x0 - 4;           // global x of stg col 0

    for (int k = 0; k < Cc / CC; ++k) {
        __syncthreads();   // previous chunk's readers done before overwrite
        // ---- stage CC channels of the x2 halo tile (zero-padded), col-major ----
        for (int idx = tid; idx < STG_SZ; idx += 256) {
            int cl  = idx / (SROWS * SCOLS);
            int rem = idx - cl * (SROWS * SCOLS);
            int r   = rem / SCOLS;          // row-major iteration: coalesced global
            int col = rem - r * SCOLS;
            int gyy = rowbase + r;
            int gxx = colbase + col;
            float v = 0.f;
            if ((unsigned)gyy < (unsigned)Hc && (unsigned)gxx < (unsigned)Wc)
                v = x2[(((bb * Cc) + (k * CC + cl)) * Hc + gyy) * Wc + gxx];
            stg[(cl * SCOLS + col) * SROWS + r] = v;   // col-major LDS write
        }
        __syncthreads();
        // ---- compute: each subset handles 2 of the CC staged channels ----
        #pragma unroll
        for (int c2 = 0; c2 < CC / 4; ++c2) {
            const int cl = sub * (CC / 4) + c2;
            const int c  = k * CC + cl;
            const float4 a4 = *reinterpret_cast<const float4*>(
                &x1[((bb * Cc + c) * Hc + (y0 + gy)) * Wc + x0 + 4 * gx]);
            const float ax[4] = {a4.x, a4.y, a4.z, a4.w};
            const float* sb = &stg[(cl * SCOLS + 4 * gx) * SROWS + gy];
            #pragma unroll
            for (int ci = 0; ci < 12; ++ci) {
                // 3 consecutive rows of one column strip (ds_read2-friendly)
                const float v0 = sb[ci * SROWS + 0];
                const float v1 = sb[ci * SROWS + 1];
                const float v2 = sb[ci * SROWS + 2];
                #pragma unroll
                for (int px = 0; px < 4; ++px) {
                    const int dxi = ci - px;
                    if (dxi >= 0 && dxi < 9) {
                        acc[0][dxi][px] += ax[px] * v0;
                        acc[1][dxi][px] += ax[px] * v1;
                        acc[2][dxi][px] += ax[px] * v2;
                    }
                }
            }
        }
    }

    // ---- reduce the 4 channel-subsets via LDS atomics (ds_add_f32) ----
    #pragma unroll
    for (int j = 0; j < NDY; ++j)
        #pragma unroll
        for (int dxi = 0; dxi < 9; ++dxi)
            #pragma unroll
            for (int px = 0; px < 4; ++px)
                atomicAdd(&accs[((j * 9 + dxi) * TW + (4 * gx + px)) * SG + gy],
                          acc[j][dxi][px]);
    __syncthreads();

    // ---- coalesced store of the 27 output planes for this tile ----
    const float inv = 1.0f / (float)Cc;
    for (int i = tid; i < 27 * TH * TW; i += 256) {
        int dl = i >> 8;            // displacement index within group (0..26)
        int p  = i & 255;
        int yy = p >> 4, xx = p & 15;
        out[((bb * 81 + g * 27 + dl) * Hc + (y0 + yy)) * Wc + (x0 + xx)] =
            accs[(dl * TW + xx) * SG + yy] * inv;
    }
}

extern "C" void kernel_launch(void* const* d_in, const int* in_sizes, int n_in,
                              void* d_out, int out_size, void* d_ws, size_t ws_size,
                              hipStream_t stream) {
    const float* x1 = (const float*)d_in[0];
    const float* x2 = (const float*)d_in[1];
    float* out = (float*)d_out;
    // grid = 3 d-groups * 8 * 8 tiles * 4 batches = 768 blocks
    dim3 grid(3 * 8 * 8 * Bc), block(256);
    corr_kernel<<<grid, block, 0, stream>>>(x1, x2, out);
}

// Round 2
// 239.662 us; speedup vs baseline: 1.9745x; 1.9745x over previous
//
#include <hip/hip_runtime.h>

// FlowNet correlation: out[b, dy*9+dx, y, x] = (1/256) sum_c x1[b,c,y,x] * x2[b,c,y+dy-4,x+dx-4]
// B=4 C=256 H=W=128, 9x9 displacements, zero padding.
//
// Round-2 design:
//  - 3 d-groups (dy = 3g + wave_id), block = 192 thr = 3 waves, tile 16x16 px.
//  - Each wave computes ONE dy for ALL channels -> acc[9][4] = 36 regs, no reduction.
//  - x2 halo tile staged row-major, row stride 48 dw (== 16 mod 32) -> conflict-free ds_read_b128.
//  - Double-buffered staging, one barrier per 4-channel chunk, hoisted slot descriptors.

#define MD 4
constexpr int Bc = 4, Cc = 256, Hc = 128, Wc = 128;
constexpr int TH = 16, TW = 16;
constexpr int NDY = 3;                  // dy per d-group (one per wave)
constexpr int CC = 4;                   // channels per chunk
constexpr int SROWS = TH + NDY - 1;     // 18 staged rows
constexpr int SCOLS = TW + 2 * MD;      // 24 staged cols
constexpr int RSC = 48;                 // padded row stride (dw), 48 % 32 == 16 -> b128 conflict-free
constexpr int CH_STRIDE = SROWS * RSC;  // 864 dw per channel
constexpr int BUF_DW = CC * CH_STRIDE;  // 3456 dw per buffer
constexpr int NF4 = CC * SROWS * (SCOLS / 4);  // 432 float4 staging slots
constexpr int NTHR = 192;
constexpr int NSLOT = 3;                // ceil(432/192)

__global__ __launch_bounds__(NTHR, 4)
void corr_kernel(const float* __restrict__ x1, const float* __restrict__ x2,
                 float* __restrict__ out)
{
    __shared__ float stg[2 * BUF_DW];   // 27648 B

    const int tid  = threadIdx.x;
    const int w    = tid >> 6;          // wave id = local dy
    const int lane = tid & 63;
    const int gy   = lane >> 2;         // 0..15 tile row
    const int gx   = lane & 3;          // 0..3  col-group (4 px each)

    int bid = blockIdx.x;
    const int g  = bid % 3;  bid /= 3;  // d-group
    const int tx = bid & 7;
    const int ty = (bid >> 3) & 7;
    const int bb = bid >> 6;
    const int x0 = tx * TW, y0 = ty * TH;
    const int rowbase = y0 + 3 * g - MD;   // global y of staged row 0

    // ---- hoisted staging slot descriptors (fixed per thread across chunks) ----
    int  s_goff[NSLOT], s_loff[NSLOT];
    bool s_val[NSLOT], s_act[NSLOT];
    #pragma unroll
    for (int s = 0; s < NSLOT; ++s) {
        int idx = tid + s * NTHR;
        bool active = idx < NF4;
        int i2  = active ? idx : 0;
        int cl  = i2 / (SROWS * 6);
        int rem = i2 - cl * (SROWS * 6);
        int r   = rem / 6;
        int gc  = rem - r * 6;
        int yy  = rowbase + r;
        int xx  = x0 - 4 + 4 * gc;              // multiple of 4: float4 all-valid or all-invalid
        s_act[s]  = active;
        s_val[s]  = active && ((unsigned)yy < (unsigned)Hc) && ((unsigned)xx < (unsigned)(Wc - 3));
        s_goff[s] = cl * (Hc * Wc) + yy * Wc + xx;
        s_loff[s] = cl * CH_STRIDE + r * RSC + 4 * gc;
    }

    const float* x2b = x2 + (size_t)bb * Cc * Hc * Wc;
    const float* x1b = x1 + (((size_t)bb * Cc) * Hc + (y0 + gy)) * Wc + x0 + 4 * gx;

    float acc[9][4];
    #pragma unroll
    for (int dx = 0; dx < 9; ++dx)
        #pragma unroll
        for (int p = 0; p < 4; ++p) acc[dx][p] = 0.f;

    const float4 f40 = make_float4(0.f, 0.f, 0.f, 0.f);
    float4 nf[NSLOT];

    // ---- prologue: stage chunk 0 into buffer 0 ----
    #pragma unroll
    for (int s = 0; s < NSLOT; ++s) {
        nf[s] = f40;
        if (s_val[s]) nf[s] = *(const float4*)(x2b + s_goff[s]);
    }
    #pragma unroll
    for (int s = 0; s < NSLOT; ++s)
        if (s_act[s]) *(float4*)(&stg[s_loff[s]]) = nf[s];

    for (int k = 0; k < Cc / CC; ++k) {
        const int pb = k & 1;
        // issue global loads for chunk k+1 (latency overlapped with compute below)
        if (k + 1 < Cc / CC) {
            const int gof = (k + 1) * CC * Hc * Wc;
            #pragma unroll
            for (int s = 0; s < NSLOT; ++s) {
                nf[s] = f40;
                if (s_val[s]) nf[s] = *(const float4*)(x2b + gof + s_goff[s]);
            }
        }
        __syncthreads();   // chunk k's buffer fully written; prev buffer's readers done
        // ---- compute chunk k ----
        #pragma unroll
        for (int cl = 0; cl < CC; ++cl) {
            const int c = k * CC + cl;
            const float4 a4 = *(const float4*)(x1b + c * (Hc * Wc));
            const float* rowp = &stg[pb * BUF_DW + cl * CH_STRIDE + (gy + w) * RSC + 4 * gx];
            const float4 q0 = *(const float4*)(rowp);
            const float4 q1 = *(const float4*)(rowp + 4);
            const float4 q2 = *(const float4*)(rowp + 8);
            const float v[12] = {q0.x, q0.y, q0.z, q0.w,
                                 q1.x, q1.y, q1.z, q1.w,
                                 q2.x, q2.y, q2.z, q2.w};
            const float a[4] = {a4.x, a4.y, a4.z, a4.w};
            #pragma unroll
            for (int dx = 0; dx < 9; ++dx)
                #pragma unroll
                for (int p = 0; p < 4; ++p)
                    acc[dx][p] += a[p] * v[dx + p];
        }
        // ---- write chunk k+1 into the other buffer (safe: after this iter's barrier) ----
        if (k + 1 < Cc / CC) {
            const int lb = ((k + 1) & 1) * BUF_DW;
            #pragma unroll
            for (int s = 0; s < NSLOT; ++s)
                if (s_act[s]) *(float4*)(&stg[lb + s_loff[s]]) = nf[s];
        }
    }

    // ---- epilogue: scale and store 9 aligned float4 per thread ----
    const float inv = 1.0f / (float)Cc;
    float* ob = out + (((size_t)bb * 81 + (3 * g + w) * 9) * Hc + (y0 + gy)) * Wc + x0 + 4 * gx;
    #pragma unroll
    for (int dx = 0; dx < 9; ++dx) {
        float4 st = make_float4(acc[dx][0] * inv, acc[dx][1] * inv,
                                acc[dx][2] * inv, acc[dx][3] * inv);
        *(float4*)(ob + dx * (Hc * Wc)) = st;
    }
}

extern "C" void kernel_launch(void* const* d_in, const int* in_sizes, int n_in,
                              void* d_out, int out_size, void* d_ws, size_t ws_size,
                              hipStream_t stream) {
    const float* x1 = (const float*)d_in[0];
    const float* x2 = (const float*)d_in[1];
    float* out = (float*)d_out;
    dim3 grid(3 * 8 * 8 * Bc), block(NTHR);   // 768 blocks x 192 threads
    corr_kernel<<<grid, block, 0, stream>>>(x1, x2, out);
}